// Round 10
// baseline (597.791 us; speedup 1.0000x reference)
//
#include <hip/hip_runtime.h>
#include <hip/hip_bf16.h>
#include <hip/hip_fp16.h>
#include <math.h>

// Problem constants
#define BB   4
#define SSQ  1024
#define DDM  512
#define HHD  8
#define KTOP 204
#define NPAT 8
#define PDIM 64

typedef unsigned long long u64;
typedef unsigned int u32;
typedef unsigned short u16;

// Polymorphic input loader: flag==1 -> f32 data, flag==0 -> bf16 data.
__device__ __forceinline__ float ldin(const void* p, size_t i, int f32) {
    if (f32) return ((const float*)p)[i];
    u16 h = ((const u16*)p)[i];
    return __uint_as_float(((u32)h) << 16);
}

__device__ __forceinline__ float bf2f(u16 h) {
    return __uint_as_float(((u32)h) << 16);
}

// fp16 pair helpers
typedef _Float16 hf2v __attribute__((ext_vector_type(2)));
union H2U { u32 u; hf2v v; __half2 h; };

__device__ __forceinline__ u32 packh2(float a, float b) {
    H2U c; c.h = __floats2half2_rn(a, b); return c.u;
}

// fused fp16 dot2 with f32 accumulate (v_dot2_f32_f16); safe fallback.
__device__ __forceinline__ float fdot2f(u32 a, u32 b, float c) {
#if __has_builtin(__builtin_amdgcn_fdot2)
    H2U ua, ub; ua.u = a; ub.u = b;
    return __builtin_amdgcn_fdot2(ua.v, ub.v, c, false);
#else
    H2U ua, ub; ua.u = a; ub.u = b;
    float2 fa = __half22float2(ua.h), fb = __half22float2(ub.h);
    return fmaf(fa.y, fb.y, fmaf(fa.x, fb.x, c));
#endif
}

// 8 packed fp16 (one uint4 load)
union U8H { uint4 u; _Float16 h[8]; };

// ---------------------------------------------------------------------------
// K0: input dtype detection (same sample set/decision as validated round 8,
// parallelized across 64 lanes).
// ---------------------------------------------------------------------------
__global__ __launch_bounds__(64)
void detect_kernel(const void* q, int* flag) {
    int lane = threadIdx.x;
    const u16* p = (const u16*)q;
    int good = 0;
    #pragma unroll
    for (int k = 0; k < 4; ++k) {
        int i = (lane * 4 + k) * 2;
        float v = __uint_as_float(((u32)p[i]) << 16);
        float a = fabsf(v);
        if (a > 0.00390625f && a < 64.f) ++good;
    }
    #pragma unroll
    for (int off = 32; off >= 1; off >>= 1) good += __shfl_xor(good, off);
    if (lane == 0) *flag = (good < 128) ? 1 : 0;
}

// ---------------------------------------------------------------------------
// K1: pattern learner -> weighted_patterns (out2, f32). One block per row.
// (loose tolerance: 4-partial chains OK)
// ---------------------------------------------------------------------------
__global__ __launch_bounds__(64)
void pattern_kernel(const void* __restrict__ q,
                    const void* __restrict__ pw1, const void* __restrict__ pb1,
                    const void* __restrict__ pw2, const void* __restrict__ pb2,
                    const void* __restrict__ bank, const void* __restrict__ gate,
                    const int* __restrict__ flagp,
                    float* __restrict__ out2) {
    __shared__ float qs[DDM];
    __shared__ float h1[PDIM];
    __shared__ float enc[PDIM];
    __shared__ float ps[NPAT];
    int f32 = *flagp;
    int row = blockIdx.x;
    int t = threadIdx.x;
    for (int i = t; i < DDM; i += 64) qs[i] = ldin(q, (size_t)row * DDM + i, f32);
    __syncthreads();
    float a0 = ldin(pb1, t, f32), a1 = 0.f, a2 = 0.f, a3 = 0.f;
    #pragma unroll 4
    for (int d = 0; d < DDM; d += 4) {
        a0 = fmaf(qs[d + 0], ldin(pw1, (size_t)(d + 0) * PDIM + t, f32), a0);
        a1 = fmaf(qs[d + 1], ldin(pw1, (size_t)(d + 1) * PDIM + t, f32), a1);
        a2 = fmaf(qs[d + 2], ldin(pw1, (size_t)(d + 2) * PDIM + t, f32), a2);
        a3 = fmaf(qs[d + 3], ldin(pw1, (size_t)(d + 3) * PDIM + t, f32), a3);
    }
    h1[t] = fmaxf((a0 + a1) + (a2 + a3), 0.f);
    __syncthreads();
    float acc2 = ldin(pb2, t, f32);
    for (int d = 0; d < PDIM; ++d) acc2 = fmaf(h1[d], ldin(pw2, (size_t)d * PDIM + t, f32), acc2);
    enc[t] = tanhf(acc2);
    __syncthreads();
    if (t < NPAT) {
        float a = 0.f;
        for (int d = 0; d < PDIM; ++d) a = fmaf(enc[d], ldin(bank, (size_t)t * PDIM + d, f32), a);
        ps[t] = a * 0.125f;
    }
    __syncthreads();
    if (t < NPAT) {
        float m = ps[0];
        for (int n = 1; n < NPAT; ++n) m = fmaxf(m, ps[n]);
        float sum = 0.f;
        for (int n = 0; n < NPAT; ++n) sum += expf(ps[n] - m);
        float e = expf(ps[t] - m);
        out2[(size_t)row * NPAT + t] = e / sum * ldin(gate, t, f32);
    }
}

// ---------------------------------------------------------------------------
// K2 v6: f32 projection (z=0:Q, 1:K, 2:V). EXACT-SENSITIVE per-element FMA
// chain UNCHANGED (k ascending, j ascending within float4 group).
// 128x64 macro-tile, 8x4 outputs/thread (the r6 transformation that took
// scoresf 118->106: FMA:LDS-read 128:12 per kk-group vs 16:8). 51KB LDS ->
// 3 blocks/CU. Vf32 is DEAD (attn uses fp16 V since r7) -> store dropped.
// fp16 K/V copies for attention retained.
// ---------------------------------------------------------------------------
__global__ __launch_bounds__(256, 2)
void projf_kernel(const void* __restrict__ query, const void* __restrict__ key,
                  const void* __restrict__ value,
                  const void* __restrict__ wq, const void* __restrict__ bq,
                  const void* __restrict__ wk, const void* __restrict__ bk,
                  const void* __restrict__ wv, const void* __restrict__ bv,
                  const int* __restrict__ flagp,
                  float* __restrict__ Qf32, float* __restrict__ Kf32,
                  u16* __restrict__ Khf, u16* __restrict__ Vhf) {
    __shared__ float Xs[128][68];
    __shared__ float Ws[64][68];
    int f32 = *flagp;
    int z = blockIdx.z;
    const void* X = (z == 0) ? query : ((z == 1) ? key : value);
    const void* W = (z == 0) ? wq : ((z == 1) ? wk : wv);
    const void* Bv = (z == 0) ? bq : ((z == 1) ? bk : bv);
    float* Y = (z == 0) ? Qf32 : Kf32;       // z==2 has no f32 output
    int c0 = blockIdx.x * 64, r0 = blockIdx.y * 128;
    int tx = threadIdx.x & 15, ty = threadIdx.x >> 4;

    // staging: X 128x64 = 2048 float4 (8/thread), W 64x64 = 1024 (4/thread)
    int xr_r[8], xr_s[8], wr_r[4], wr_s[4];
    #pragma unroll
    for (int it = 0; it < 8; ++it) {
        int idx = threadIdx.x + it * 256;
        xr_r[it] = idx >> 4;      // 0..127
        xr_s[it] = idx & 15;
    }
    #pragma unroll
    for (int it = 0; it < 4; ++it) {
        int idx = threadIdx.x + it * 256;
        wr_r[it] = idx >> 4;      // 0..63
        wr_s[it] = idx & 15;
    }

    float4 xr[8], wr[4];
    if (f32) {
        #pragma unroll
        for (int it = 0; it < 8; ++it)
            xr[it] = *reinterpret_cast<const float4*>((const float*)X + (size_t)(r0 + xr_r[it]) * DDM + xr_s[it] * 4);
        #pragma unroll
        for (int it = 0; it < 4; ++it)
            wr[it] = *reinterpret_cast<const float4*>((const float*)W + (size_t)wr_r[it] * DDM + c0 + wr_s[it] * 4);
    } else {
        #pragma unroll
        for (int it = 0; it < 8; ++it) {
            ushort4 xh = *reinterpret_cast<const ushort4*>((const u16*)X + (size_t)(r0 + xr_r[it]) * DDM + xr_s[it] * 4);
            xr[it] = make_float4(bf2f(xh.x), bf2f(xh.y), bf2f(xh.z), bf2f(xh.w));
        }
        #pragma unroll
        for (int it = 0; it < 4; ++it) {
            ushort4 wh = *reinterpret_cast<const ushort4*>((const u16*)W + (size_t)wr_r[it] * DDM + c0 + wr_s[it] * 4);
            wr[it] = make_float4(bf2f(wh.x), bf2f(wh.y), bf2f(wh.z), bf2f(wh.w));
        }
    }

    float acc[8][4] = {};
    for (int k0 = 0; k0 < DDM; k0 += 64) {
        __syncthreads();
        #pragma unroll
        for (int it = 0; it < 8; ++it)
            *reinterpret_cast<float4*>(&Xs[xr_r[it]][xr_s[it] * 4]) = xr[it];
        #pragma unroll
        for (int it = 0; it < 4; ++it)
            *reinterpret_cast<float4*>(&Ws[wr_r[it]][wr_s[it] * 4]) = wr[it];
        __syncthreads();
        int kn = k0 + 64;
        if (kn < DDM) {
            if (f32) {
                #pragma unroll
                for (int it = 0; it < 8; ++it)
                    xr[it] = *reinterpret_cast<const float4*>((const float*)X + (size_t)(r0 + xr_r[it]) * DDM + kn + xr_s[it] * 4);
                #pragma unroll
                for (int it = 0; it < 4; ++it)
                    wr[it] = *reinterpret_cast<const float4*>((const float*)W + (size_t)(kn + wr_r[it]) * DDM + c0 + wr_s[it] * 4);
            } else {
                #pragma unroll
                for (int it = 0; it < 8; ++it) {
                    ushort4 xh = *reinterpret_cast<const ushort4*>((const u16*)X + (size_t)(r0 + xr_r[it]) * DDM + kn + xr_s[it] * 4);
                    xr[it] = make_float4(bf2f(xh.x), bf2f(xh.y), bf2f(xh.z), bf2f(xh.w));
                }
                #pragma unroll
                for (int it = 0; it < 4; ++it) {
                    ushort4 wh = *reinterpret_cast<const ushort4*>((const u16*)W + (size_t)(kn + wr_r[it]) * DDM + c0 + wr_s[it] * 4);
                    wr[it] = make_float4(bf2f(wh.x), bf2f(wh.y), bf2f(wh.z), bf2f(wh.w));
                }
            }
        }
        // EXACT compute (unchanged chain): sub-k ascending per output element
        #pragma unroll 2
        for (int kk = 0; kk < 64; kk += 4) {
            float4 xv[8];
            #pragma unroll
            for (int a = 0; a < 8; ++a)
                xv[a] = *reinterpret_cast<const float4*>(&Xs[ty + 16 * a][kk]);
            #pragma unroll
            for (int j = 0; j < 4; ++j) {
                float4 wv = *reinterpret_cast<const float4*>(&Ws[kk + j][4 * tx]);
                #pragma unroll
                for (int a = 0; a < 8; ++a) {
                    float x = ((const float*)&xv[a])[j];
                    acc[a][0] = fmaf(x, wv.x, acc[a][0]);
                    acc[a][1] = fmaf(x, wv.y, acc[a][1]);
                    acc[a][2] = fmaf(x, wv.z, acc[a][2]);
                    acc[a][3] = fmaf(x, wv.w, acc[a][3]);
                }
            }
        }
    }
    #pragma unroll
    for (int a = 0; a < 8; ++a) {
        int r = r0 + ty + 16 * a;
        float4 o;
        o.x = acc[a][0] + ldin(Bv, c0 + 4 * tx + 0, f32);
        o.y = acc[a][1] + ldin(Bv, c0 + 4 * tx + 1, f32);
        o.z = acc[a][2] + ldin(Bv, c0 + 4 * tx + 2, f32);
        o.w = acc[a][3] + ldin(Bv, c0 + 4 * tx + 3, f32);
        if (z != 2)
            *reinterpret_cast<float4*>(&Y[(size_t)r * DDM + c0 + 4 * tx]) = o;
        if (z != 0) {
            uint2 ph;
            ph.x = packh2(o.x, o.y);
            ph.y = packh2(o.z, o.w);
            u16* dst = (z == 1) ? Khf : Vhf;
            *reinterpret_cast<uint2*>(&dst[(size_t)r * DDM + c0 + 4 * tx]) = ph;
        }
    }
}

// ---------------------------------------------------------------------------
// K3 v4 (REVERTED to round-6 best-total version): f32 scores. EXACT-SENSITIVE
// per-element FMA chain UNCHANGED. 128x64 macro-tile, 8x4/thread, 256 threads.
// Three structural variants (r6/r7/r8) all land 104-108us -> structural floor
// for the exact-chain constraint; this is the best-total config.
// ---------------------------------------------------------------------------
__global__ __launch_bounds__(256, 2)
void scoresf_kernel(const float* __restrict__ Qf32, const float* __restrict__ Kf32,
                    float* __restrict__ S3f) {
    __shared__ float Qs[128][68];
    __shared__ float Ks[64][68];
    int b = blockIdx.z;
    const float* Qb = Qf32 + (size_t)b * SSQ * DDM;
    const float* Kb = Kf32 + (size_t)b * SSQ * DDM;
    float* S3 = S3f + (size_t)b * SSQ * SSQ;
    int j0 = blockIdx.x * 64, i0 = blockIdx.y * 128;
    int tx = threadIdx.x & 15, ty = threadIdx.x >> 4;

    int qr_r[8], qr_s[8], kr_r[4], kr_s[4];
    #pragma unroll
    for (int it = 0; it < 8; ++it) {
        int idx = threadIdx.x + it * 256;
        qr_r[it] = idx >> 4;
        qr_s[it] = idx & 15;
    }
    #pragma unroll
    for (int it = 0; it < 4; ++it) {
        int idx = threadIdx.x + it * 256;
        kr_r[it] = idx >> 4;
        kr_s[it] = idx & 15;
    }

    float4 qr[8], kr[4];
    #pragma unroll
    for (int it = 0; it < 8; ++it)
        qr[it] = *reinterpret_cast<const float4*>(Qb + (size_t)(i0 + qr_r[it]) * DDM + qr_s[it] * 4);
    #pragma unroll
    for (int it = 0; it < 4; ++it)
        kr[it] = *reinterpret_cast<const float4*>(Kb + (size_t)(j0 + kr_r[it]) * DDM + kr_s[it] * 4);

    float acc[8][4] = {};
    for (int k0 = 0; k0 < DDM; k0 += 64) {
        __syncthreads();
        #pragma unroll
        for (int it = 0; it < 8; ++it)
            *reinterpret_cast<float4*>(&Qs[qr_r[it]][qr_s[it] * 4]) = qr[it];
        #pragma unroll
        for (int it = 0; it < 4; ++it)
            *reinterpret_cast<float4*>(&Ks[kr_r[it]][kr_s[it] * 4]) = kr[it];
        __syncthreads();
        int kn = k0 + 64;
        if (kn < DDM) {
            #pragma unroll
            for (int it = 0; it < 8; ++it)
                qr[it] = *reinterpret_cast<const float4*>(Qb + (size_t)(i0 + qr_r[it]) * DDM + kn + qr_s[it] * 4);
            #pragma unroll
            for (int it = 0; it < 4; ++it)
                kr[it] = *reinterpret_cast<const float4*>(Kb + (size_t)(j0 + kr_r[it]) * DDM + kn + kr_s[it] * 4);
        }
        #pragma unroll 2
        for (int kk = 0; kk < 64; kk += 4) {
            float4 qv[8], kv[4];
            #pragma unroll
            for (int a = 0; a < 8; ++a)
                qv[a] = *reinterpret_cast<const float4*>(&Qs[ty + 16 * a][kk]);
            #pragma unroll
            for (int b2 = 0; b2 < 4; ++b2)
                kv[b2] = *reinterpret_cast<const float4*>(&Ks[tx + 16 * b2][kk]);
            #pragma unroll
            for (int a = 0; a < 8; ++a)
                #pragma unroll
                for (int b2 = 0; b2 < 4; ++b2) {   // .x,.y,.z,.w ascending: exact
                    acc[a][b2] = fmaf(qv[a].x, kv[b2].x, acc[a][b2]);
                    acc[a][b2] = fmaf(qv[a].y, kv[b2].y, acc[a][b2]);
                    acc[a][b2] = fmaf(qv[a].z, kv[b2].z, acc[a][b2]);
                    acc[a][b2] = fmaf(qv[a].w, kv[b2].w, acc[a][b2]);
                }
        }
    }
    __syncthreads();
    #pragma unroll
    for (int a = 0; a < 8; ++a)
        #pragma unroll
        for (int b2 = 0; b2 < 4; ++b2)
            Qs[ty + 16 * a][tx + 16 * b2] = acc[a][b2] * 0.125f;
    __syncthreads();
    #pragma unroll
    for (int it = 0; it < 8; ++it) {
        int row = qr_r[it], q4 = qr_s[it];
        float4 o = *reinterpret_cast<const float4*>(&Qs[row][q4 * 4]);
        *reinterpret_cast<float4*>(&S3[(size_t)(i0 + row) * SSQ + j0 + q4 * 4]) = o;
    }
}

// ---------------------------------------------------------------------------
// K4 v2: per-row top-204 via 4-pass radix select (validated) + compact
// column lists (validated round 7).
// ---------------------------------------------------------------------------
__global__ __launch_bounds__(256)
void maskselect_kernel(const float* __restrict__ S3f,
                       u64* __restrict__ bitmask,     // (B*S, 16)
                       u16* __restrict__ lists) {     // (B*S, 256)
    __shared__ u32 keys[1024];
    __shared__ u32 sel[1024];
    __shared__ u32 hist[256];
    __shared__ u32 ssum[256];
    __shared__ u32 scan[256];
    __shared__ u32 pick_digit, pick_rem;
    int i = blockIdx.x, b = blockIdx.y;
    int t = threadIdx.x;
    const float* srow = S3f + (size_t)b * SSQ * SSQ + (size_t)i * SSQ;
    for (int j = t; j < 1024; j += 256) {
        u32 bits = __float_as_uint(srow[j]);
        keys[j] = (bits & 0x80000000u) ? ~bits : (bits | 0x80000000u);
    }
    __syncthreads();
    u32 prefix = 0, himask = 0, rem = KTOP;
    for (int p = 3; p >= 0; --p) {
        int shift = p * 8;
        hist[t] = 0;
        __syncthreads();
        for (int j = t; j < 1024; j += 256) {
            u32 kb = keys[j];
            if ((kb & himask) == prefix) atomicAdd(&hist[(kb >> shift) & 0xFFu], 1u);
        }
        __syncthreads();
        ssum[t] = hist[t];
        __syncthreads();
        for (int off = 1; off < 256; off <<= 1) {
            u32 v = (t + off < 256) ? ssum[t + off] : 0u;
            __syncthreads();
            ssum[t] += v;
            __syncthreads();
        }
        u32 nxt = (t < 255) ? ssum[t + 1] : 0u;
        if (ssum[t] >= rem && nxt < rem) { pick_digit = (u32)t; pick_rem = rem - nxt; }
        __syncthreads();
        prefix |= pick_digit << shift;
        rem = pick_rem;
        himask |= (0xFFu << shift);
        __syncthreads();
    }
    u32 vstar = prefix;
    u32 tneed = rem;
    u32 eq[4]; u32 local = 0;
    #pragma unroll
    for (int a = 0; a < 4; ++a) {
        int j = 4 * t + a;
        u32 kb = keys[j];
        sel[j] = (kb > vstar) ? 1u : 0u;
        eq[a] = (kb == vstar) ? 1u : 0u;
        local += eq[a];
    }
    scan[t] = local;
    __syncthreads();
    for (int off = 1; off < 256; off <<= 1) {
        u32 v = (t >= off) ? scan[t - off] : 0u;
        __syncthreads();
        scan[t] += v;
        __syncthreads();
    }
    u32 base = (t > 0) ? scan[t - 1] : 0u;
    #pragma unroll
    for (int a = 0; a < 4; ++a) {
        if (eq[a]) { if (base < tneed) sel[4 * t + a] = 1u; base += 1; }
    }
    __syncthreads();
    if (t < 16) {
        u64 wbits = 0;
        for (int l = 0; l < 64; ++l)
            if (sel[t * 64 + l]) wbits |= (1ull << l);
        bitmask[((size_t)b * SSQ + i) * 16 + t] = wbits;
    }
    // --- compact selected columns (exactly KTOP, ascending order) ---
    u32 ones = sel[4 * t] + sel[4 * t + 1] + sel[4 * t + 2] + sel[4 * t + 3];
    scan[t] = ones;
    __syncthreads();
    for (int off = 1; off < 256; off <<= 1) {
        u32 v = (t >= off) ? scan[t - off] : 0u;
        __syncthreads();
        scan[t] += v;
        __syncthreads();
    }
    u32 pos = scan[t] - ones;
    u16* lrow = lists + ((size_t)b * SSQ + i) * 256;
    #pragma unroll
    for (int a = 0; a < 4; ++a) {
        if (sel[4 * t + a]) lrow[pos++] = (u16)(4 * t + a);
    }
    if (t < 52) lrow[KTOP + t] = 0;   // pad tail (keeps garbage out of staging)
}

// ---------------------------------------------------------------------------
// K5 v5: sparse attention. One wave per (b,h,i) row. Loose-tolerance path.
//  - column list precomputed by maskselect (cnt == KTOP always).
//  - score phase: fp16 K + v_dot2_f32_f16, 4 lanes/column (validated).
//  - V phase: fp16 V + v_fma_mix_f32, 8 lanes/entry (validated).
// ---------------------------------------------------------------------------
__global__ __launch_bounds__(256, 8)
void attn_sparse_kernel(const float* __restrict__ Qf32, const u16* __restrict__ Khf,
                        const u16* __restrict__ Vhf, const u16* __restrict__ lists,
                        float* __restrict__ AO) {
    __shared__ float pbuf[4][256];
    __shared__ uint2 lraw[4][64];
    int lane = threadIdx.x & 63, w = threadIdx.x >> 6;
    int b = blockIdx.z, h = blockIdx.y, i = blockIdx.x * 4 + w;
    size_t qoff = ((size_t)(b * SSQ + i)) * DDM + h * 64;

    // --- stage precomputed column list (256 u16 = 64 x uint2) ---
    const uint2* Lrow = reinterpret_cast<const uint2*>(lists + ((size_t)(b * SSQ + i)) * 256);
    lraw[w][lane] = Lrow[lane];
    const u16* list = reinterpret_cast<const u16*>(lraw[w]);

    // --- score phase: 16 columns/iter, 4 lanes cooperate per column ---
    int sub = lane & 3;        // dim-octet selector
    int g   = lane >> 2;       // column group 0..15
    u32 qh[8];                 // Q dims {sub*8..+8} and {32+sub*8..+8} as fp16 pairs
    {
        float4 qa = *reinterpret_cast<const float4*>(&Qf32[qoff + sub * 8]);
        float4 qb = *reinterpret_cast<const float4*>(&Qf32[qoff + sub * 8 + 4]);
        float4 qc = *reinterpret_cast<const float4*>(&Qf32[qoff + 32 + sub * 8]);
        float4 qd = *reinterpret_cast<const float4*>(&Qf32[qoff + 32 + sub * 8 + 4]);
        qh[0] = packh2(qa.x, qa.y); qh[1] = packh2(qa.z, qa.w);
        qh[2] = packh2(qb.x, qb.y); qh[3] = packh2(qb.z, qb.w);
        qh[4] = packh2(qc.x, qc.y); qh[5] = packh2(qc.z, qc.w);
        qh[6] = packh2(qd.x, qd.y); qh[7] = packh2(qd.z, qd.w);
    }

    const u16* Kb = Khf + (size_t)b * SSQ * DDM + h * 64 + sub * 8;
    float m = -1e30f;
    for (int base = 0; base < KTOP; base += 16) {
        int idx = base + g;
        int valid = (idx < KTOP);
        int j = valid ? (int)list[idx] : 0;
        const u16* kr = Kb + (size_t)j * DDM;
        uint4 k0 = *reinterpret_cast<const uint4*>(kr);        // dims sub*8..+8 (line 0)
        uint4 k1 = *reinterpret_cast<const uint4*>(kr + 32);   // dims 32+sub*8..+8 (line 1)
        float p = fdot2f(qh[0], k0.x, 0.f);
        p = fdot2f(qh[1], k0.y, p);
        p = fdot2f(qh[2], k0.z, p);
        p = fdot2f(qh[3], k0.w, p);
        p = fdot2f(qh[4], k1.x, p);
        p = fdot2f(qh[5], k1.y, p);
        p = fdot2f(qh[6], k1.z, p);
        p = fdot2f(qh[7], k1.w, p);
        p += __shfl_xor(p, 1);
        p += __shfl_xor(p, 2);
        float s = valid ? p * 0.125f : -1e30f;
        m = fmaxf(m, s);
        if (valid && sub == 0) pbuf[w][idx] = s;
    }
    #pragma unroll
    for (int off = 32; off >= 1; off >>= 1) m = fmaxf(m, __shfl_xor(m, off));

    // --- softmax: exp in place, wave-sum ---
    float lsum = 0.f;
    for (int idx = lane; idx < KTOP; idx += 64) {
        float p = expf(pbuf[w][idx] - m);
        pbuf[w][idx] = p;
        lsum += p;
    }
    #pragma unroll
    for (int off = 32; off >= 1; off >>= 1) lsum += __shfl_xor(lsum, off);

    // --- V phase: 8 entries/iter, 8 lanes each owning 8 dims (fma_mix) ---
    int vg = lane >> 3, vl = lane & 7;
    const u16* Vb = Vhf + (size_t)b * SSQ * DDM + h * 64 + vl * 8;
    float ac[8] = {};
    #pragma unroll 2
    for (int tt = 0; tt < KTOP; tt += 8) {
        int e = tt + vg;
        if (e < KTOP) {
            int j = (int)list[e];
            float pwt = pbuf[w][e];
            U8H vv;
            vv.u = *reinterpret_cast<const uint4*>(Vb + (size_t)j * DDM);
            ac[0] = fmaf((float)vv.h[0], pwt, ac[0]);
            ac[1] = fmaf((float)vv.h[1], pwt, ac[1]);
            ac[2] = fmaf((float)vv.h[2], pwt, ac[2]);
            ac[3] = fmaf((float)vv.h[3], pwt, ac[3]);
            ac[4] = fmaf((float)vv.h[4], pwt, ac[4]);
            ac[5] = fmaf((float)vv.h[5], pwt, ac[5]);
            ac[6] = fmaf((float)vv.h[6], pwt, ac[6]);
            ac[7] = fmaf((float)vv.h[7], pwt, ac[7]);
        }
    }
    #pragma unroll
    for (int off = 8; off <= 32; off <<= 1) {
        #pragma unroll
        for (int t = 0; t < 8; ++t) ac[t] += __shfl_xor(ac[t], off);
    }
    if (vg == 0) {
        float inv = 1.0f / lsum;
        float4 o0, o1;
        o0.x = ac[0] * inv; o0.y = ac[1] * inv; o0.z = ac[2] * inv; o0.w = ac[3] * inv;
        o1.x = ac[4] * inv; o1.y = ac[5] * inv; o1.z = ac[6] * inv; o1.w = ac[7] * inv;
        *reinterpret_cast<float4*>(&AO[qoff + vl * 8]) = o0;
        *reinterpret_cast<float4*>(&AO[qoff + vl * 8 + 4]) = o1;
    }
}

// ---------------------------------------------------------------------------
// K6 v3: output projection  out0 = AO @ wo + bo  (f32 out, loose tolerance)
// 128x64 macro-tile, 8x4/thread (r6 transformation), reg-prefetch pipeline.
// Per-element chain unchanged (k ascending).
// ---------------------------------------------------------------------------
__global__ __launch_bounds__(256, 2)
void outproj_kernel(const float* __restrict__ AO, const void* __restrict__ wo,
                    const void* __restrict__ bo, const int* __restrict__ flagp,
                    float* __restrict__ out0) {
    __shared__ float Xs[128][68];
    __shared__ float Ws[64][68];
    int f32 = *flagp;
    int c0 = blockIdx.x * 64, r0 = blockIdx.y * 128;
    int tx = threadIdx.x & 15, ty = threadIdx.x >> 4;

    int xr_r[8], xr_s[8], wr_r[4], wr_s[4];
    #pragma unroll
    for (int it = 0; it < 8; ++it) {
        int idx = threadIdx.x + it * 256;
        xr_r[it] = idx >> 4;
        xr_s[it] = idx & 15;
    }
    #pragma unroll
    for (int it = 0; it < 4; ++it) {
        int idx = threadIdx.x + it * 256;
        wr_r[it] = idx >> 4;
        wr_s[it] = idx & 15;
    }

    float4 xr[8], wr[4];
    #pragma unroll
    for (int it = 0; it < 8; ++it)
        xr[it] = *reinterpret_cast<const float4*>(AO + (size_t)(r0 + xr_r[it]) * DDM + xr_s[it] * 4);
    if (f32) {
        #pragma unroll
        for (int it = 0; it < 4; ++it)
            wr[it] = *reinterpret_cast<const float4*>((const float*)wo + (size_t)wr_r[it] * DDM + c0 + wr_s[it] * 4);
    } else {
        #pragma unroll
        for (int it = 0; it < 4; ++it) {
            ushort4 wh = *reinterpret_cast<const ushort4*>((const u16*)wo + (size_t)wr_r[it] * DDM + c0 + wr_s[it] * 4);
            wr[it] = make_float4(bf2f(wh.x), bf2f(wh.y), bf2f(wh.z), bf2f(wh.w));
        }
    }

    float acc[8][4] = {};
    for (int k0 = 0; k0 < DDM; k0 += 64) {
        __syncthreads();
        #pragma unroll
        for (int it = 0; it < 8; ++it)
            *reinterpret_cast<float4*>(&Xs[xr_r[it]][xr_s[it] * 4]) = xr[it];
        #pragma unroll
        for (int it = 0; it < 4; ++it)
            *reinterpret_cast<float4*>(&Ws[wr_r[it]][wr_s[it] * 4]) = wr[it];
        __syncthreads();
        int kn = k0 + 64;
        if (kn < DDM) {
            #pragma unroll
            for (int it = 0; it < 8; ++it)
                xr[it] = *reinterpret_cast<const float4*>(AO + (size_t)(r0 + xr_r[it]) * DDM + kn + xr_s[it] * 4);
            if (f32) {
                #pragma unroll
                for (int it = 0; it < 4; ++it)
                    wr[it] = *reinterpret_cast<const float4*>((const float*)wo + (size_t)(kn + wr_r[it]) * DDM + c0 + wr_s[it] * 4);
            } else {
                #pragma unroll
                for (int it = 0; it < 4; ++it) {
                    ushort4 wh = *reinterpret_cast<const ushort4*>((const u16*)wo + (size_t)(kn + wr_r[it]) * DDM + c0 + wr_s[it] * 4);
                    wr[it] = make_float4(bf2f(wh.x), bf2f(wh.y), bf2f(wh.z), bf2f(wh.w));
                }
            }
        }
        #pragma unroll 2
        for (int kk = 0; kk < 64; kk += 4) {
            float4 xv[8];
            #pragma unroll
            for (int a = 0; a < 8; ++a)
                xv[a] = *reinterpret_cast<const float4*>(&Xs[ty + 16 * a][kk]);
            #pragma unroll
            for (int j = 0; j < 4; ++j) {
                float4 wv = *reinterpret_cast<const float4*>(&Ws[kk + j][4 * tx]);
                #pragma unroll
                for (int a = 0; a < 8; ++a) {
                    float x = ((const float*)&xv[a])[j];
                    acc[a][0] = fmaf(x, wv.x, acc[a][0]);
                    acc[a][1] = fmaf(x, wv.y, acc[a][1]);
                    acc[a][2] = fmaf(x, wv.z, acc[a][2]);
                    acc[a][3] = fmaf(x, wv.w, acc[a][3]);
                }
            }
        }
    }
    #pragma unroll
    for (int a = 0; a < 8; ++a) {
        int r = r0 + ty + 16 * a;
        float4 o;
        o.x = acc[a][0] + ldin(bo, c0 + 4 * tx + 0, f32);
        o.y = acc[a][1] + ldin(bo, c0 + 4 * tx + 1, f32);
        o.z = acc[a][2] + ldin(bo, c0 + 4 * tx + 2, f32);
        o.w = acc[a][3] + ldin(bo, c0 + 4 * tx + 3, f32);
        *reinterpret_cast<float4*>(&out0[(size_t)r * DDM + c0 + 4 * tx]) = o;
    }
}

// ---------------------------------------------------------------------------
// K7 (last): expand bitmask -> f32 mask for all 8 heads, overwriting ALL of
// out1 (which served as scratch until now). One block per (b,i) row.
// ---------------------------------------------------------------------------
__global__ __launch_bounds__(256)
void maskwrite_kernel(const u64* __restrict__ bitmask,
                      float* __restrict__ out1) {
    int row = blockIdx.x;            // b*S + i
    int t = threadIdx.x;
    int b = row >> 10, i = row & 1023;
    const u64* mb = bitmask + (size_t)row * 16;
    int j0 = t * 4;
    u64 w0 = mb[j0 >> 6];
    float4 v4;
    v4.x = ((w0 >> (j0 & 63)) & 1ull) ? 1.0f : 0.0f;
    v4.y = ((w0 >> ((j0 + 1) & 63)) & 1ull) ? 1.0f : 0.0f;
    v4.z = ((w0 >> ((j0 + 2) & 63)) & 1ull) ? 1.0f : 0.0f;
    v4.w = ((w0 >> ((j0 + 3) & 63)) & 1ull) ? 1.0f : 0.0f;
    for (int h = 0; h < HHD; ++h) {
        size_t base_o = (((size_t)b * HHD + h) * SSQ + i) * SSQ;
        *reinterpret_cast<float4*>(out1 + base_o + (size_t)t * 4) = v4;
    }
}

// ---------------------------------------------------------------------------
extern "C" void kernel_launch(void* const* d_in, const int* in_sizes, int n_in,
                              void* d_out, int out_size, void* d_ws, size_t ws_size,
                              hipStream_t stream) {
    const void* query = d_in[0];
    const void* key   = d_in[1];
    const void* value = d_in[2];
    const void* wq = d_in[3];  const void* bq = d_in[4];
    const void* wk = d_in[5];  const void* bk = d_in[6];
    const void* wv = d_in[7];  const void* bv = d_in[8];
    const void* wo = d_in[9];  const void* bo = d_in[10];
    const void* pw1 = d_in[11]; const void* pb1 = d_in[12];
    const void* pw2 = d_in[13]; const void* pb2 = d_in[14];
    const void* pattern_bank = d_in[15];
    const void* pattern_gate = d_in[16];

    // Outputs are FLOAT32 (validated round 8).
    float* out0 = (float*)d_out;                          // (B,S,D)   2M f32
    float* out1 = out0 + (size_t)BB * SSQ * DDM;          // (B,H,S,S) 33.5M f32 (134MB)
    float* out2 = out1 + (size_t)BB * HHD * SSQ * SSQ;    // (B,S,NP)  32K f32

    // d_ws: tiny header only (dtype flag + 512KB bitmask).
    int* flag = (int*)d_ws;
    u64* bitmask = (u64*)((char*)d_ws + 65536);           // (B*S,16) = 512KB

    // All large scratch lives INSIDE out1's 134MB, overwritten by maskwrite.
    char* SCR = (char*)out1;
    float* Qf32 = (float*)(SCR);                          // [0,8M)
    float* Kf32 = (float*)(SCR + (8ull << 20));           // [8M,16M)
    float* AO   = (float*)(SCR + (24ull << 20));          // [24M,32M)
    float* S3f  = (float*)(SCR + (32ull << 20));          // [32M,48M) all-batch scores
    u16*   Khf  = (u16*)  (SCR + (48ull << 20));          // [48M,52M) fp16 K
    u16*   Vhf  = (u16*)  (SCR + (52ull << 20));          // [52M,56M) fp16 V
    u16*   lists= (u16*)  (SCR + (56ull << 20));          // [56M,58M) column lists

    detect_kernel<<<dim3(1), dim3(64), 0, stream>>>(query, flag);

    pattern_kernel<<<dim3(BB * SSQ), dim3(64), 0, stream>>>(
        query, pw1, pb1, pw2, pb2, pattern_bank, pattern_gate, flag, out2);

    // f32 Q/K projections + fp16 K/V (exact sequential-FMA-chain semantics;
    // Vf32 dead since attn moved to fp16 V)
    projf_kernel<<<dim3(DDM / 64, BB * SSQ / 128, 3), dim3(256), 0, stream>>>(
        query, key, value, wq, bq, wk, bk, wv, bv, flag, Qf32, Kf32, Khf, Vhf);

    // f32 scores, all batches in one launch (128x64 macro-tile, best-total cfg)
    scoresf_kernel<<<dim3(SSQ / 64, SSQ / 128, BB), dim3(256), 0, stream>>>(
        Qf32, Kf32, S3f);

    // top-204 per row + compacted column lists
    maskselect_kernel<<<dim3(SSQ, BB), dim3(256), 0, stream>>>(S3f, bitmask, lists);

    // sparse attention over the 204 active columns (fp16 K dot2, fp16 V fma_mix)
    attn_sparse_kernel<<<dim3(SSQ / 4, HHD, BB), dim3(256), 0, stream>>>(
        Qf32, Khf, Vhf, lists, AO);

    outproj_kernel<<<dim3(DDM / 64, BB * SSQ / 128), dim3(256), 0, stream>>>(
        AO, wo, bo, flag, out0);

    // LAST: expand bitmask into out1 (f32 mask), erasing all scratch
    maskwrite_kernel<<<dim3(BB * SSQ), dim3(256), 0, stream>>>(bitmask, out1);
}

// Round 11
// 565.079 us; speedup vs baseline: 1.0579x; 1.0579x over previous
//
#include <hip/hip_runtime.h>
#include <hip/hip_bf16.h>
#include <hip/hip_fp16.h>
#include <math.h>

// Problem constants
#define BB   4
#define SSQ  1024
#define DDM  512
#define HHD  8
#define KTOP 204
#define NPAT 8
#define PDIM 64

typedef unsigned long long u64;
typedef unsigned int u32;
typedef unsigned short u16;

// Polymorphic input loader: flag==1 -> f32 data, flag==0 -> bf16 data.
__device__ __forceinline__ float ldin(const void* p, size_t i, int f32) {
    if (f32) return ((const float*)p)[i];
    u16 h = ((const u16*)p)[i];
    return __uint_as_float(((u32)h) << 16);
}

__device__ __forceinline__ float bf2f(u16 h) {
    return __uint_as_float(((u32)h) << 16);
}

// fp16 pair helpers
typedef _Float16 hf2v __attribute__((ext_vector_type(2)));
union H2U { u32 u; hf2v v; __half2 h; };

__device__ __forceinline__ u32 packh2(float a, float b) {
    H2U c; c.h = __floats2half2_rn(a, b); return c.u;
}

// fused fp16 dot2 with f32 accumulate (v_dot2_f32_f16); safe fallback.
__device__ __forceinline__ float fdot2f(u32 a, u32 b, float c) {
#if __has_builtin(__builtin_amdgcn_fdot2)
    H2U ua, ub; ua.u = a; ub.u = b;
    return __builtin_amdgcn_fdot2(ua.v, ub.v, c, false);
#else
    H2U ua, ub; ua.u = a; ub.u = b;
    float2 fa = __half22float2(ua.h), fb = __half22float2(ub.h);
    return fmaf(fa.y, fb.y, fmaf(fa.x, fb.x, c));
#endif
}

// 8 packed fp16 (one uint4 load)
union U8H { uint4 u; _Float16 h[8]; };

// ---------------------------------------------------------------------------
// K0: input dtype detection (same sample set/decision as validated round 8,
// parallelized across 64 lanes).
// ---------------------------------------------------------------------------
__global__ __launch_bounds__(64)
void detect_kernel(const void* q, int* flag) {
    int lane = threadIdx.x;
    const u16* p = (const u16*)q;
    int good = 0;
    #pragma unroll
    for (int k = 0; k < 4; ++k) {
        int i = (lane * 4 + k) * 2;
        float v = __uint_as_float(((u32)p[i]) << 16);
        float a = fabsf(v);
        if (a > 0.00390625f && a < 64.f) ++good;
    }
    #pragma unroll
    for (int off = 32; off >= 1; off >>= 1) good += __shfl_xor(good, off);
    if (lane == 0) *flag = (good < 128) ? 1 : 0;
}

// ---------------------------------------------------------------------------
// K1: pattern learner -> weighted_patterns (out2, f32). One block per row.
// (loose tolerance: 4-partial chains OK)
// ---------------------------------------------------------------------------
__global__ __launch_bounds__(64)
void pattern_kernel(const void* __restrict__ q,
                    const void* __restrict__ pw1, const void* __restrict__ pb1,
                    const void* __restrict__ pw2, const void* __restrict__ pb2,
                    const void* __restrict__ bank, const void* __restrict__ gate,
                    const int* __restrict__ flagp,
                    float* __restrict__ out2) {
    __shared__ float qs[DDM];
    __shared__ float h1[PDIM];
    __shared__ float enc[PDIM];
    __shared__ float ps[NPAT];
    int f32 = *flagp;
    int row = blockIdx.x;
    int t = threadIdx.x;
    for (int i = t; i < DDM; i += 64) qs[i] = ldin(q, (size_t)row * DDM + i, f32);
    __syncthreads();
    float a0 = ldin(pb1, t, f32), a1 = 0.f, a2 = 0.f, a3 = 0.f;
    #pragma unroll 4
    for (int d = 0; d < DDM; d += 4) {
        a0 = fmaf(qs[d + 0], ldin(pw1, (size_t)(d + 0) * PDIM + t, f32), a0);
        a1 = fmaf(qs[d + 1], ldin(pw1, (size_t)(d + 1) * PDIM + t, f32), a1);
        a2 = fmaf(qs[d + 2], ldin(pw1, (size_t)(d + 2) * PDIM + t, f32), a2);
        a3 = fmaf(qs[d + 3], ldin(pw1, (size_t)(d + 3) * PDIM + t, f32), a3);
    }
    h1[t] = fmaxf((a0 + a1) + (a2 + a3), 0.f);
    __syncthreads();
    float acc2 = ldin(pb2, t, f32);
    for (int d = 0; d < PDIM; ++d) acc2 = fmaf(h1[d], ldin(pw2, (size_t)d * PDIM + t, f32), acc2);
    enc[t] = tanhf(acc2);
    __syncthreads();
    if (t < NPAT) {
        float a = 0.f;
        for (int d = 0; d < PDIM; ++d) a = fmaf(enc[d], ldin(bank, (size_t)t * PDIM + d, f32), a);
        ps[t] = a * 0.125f;
    }
    __syncthreads();
    if (t < NPAT) {
        float m = ps[0];
        for (int n = 1; n < NPAT; ++n) m = fmaxf(m, ps[n]);
        float sum = 0.f;
        for (int n = 0; n < NPAT; ++n) sum += expf(ps[n] - m);
        float e = expf(ps[t] - m);
        out2[(size_t)row * NPAT + t] = e / sum * ldin(gate, t, f32);
    }
}

// ---------------------------------------------------------------------------
// K2 v5b (r7 configuration + dead-store fix): f32 projection (z=0:Q, 1:K,
// 2:V). EXACT-SENSITIVE compute loop UNCHANGED. 64x64 tile, 4x4/thread,
// 4 blocks/CU (validated best for this kernel's reuse geometry; the 128x64
// retile regressed it in r10). z==2 (V) writes ONLY the fp16 copy — Vf32 is
// dead since attn moved to fp16 V (r7).
// ---------------------------------------------------------------------------
__global__ __launch_bounds__(256, 4)
void projf_kernel(const void* __restrict__ query, const void* __restrict__ key,
                  const void* __restrict__ value,
                  const void* __restrict__ wq, const void* __restrict__ bq,
                  const void* __restrict__ wk, const void* __restrict__ bk,
                  const void* __restrict__ wv, const void* __restrict__ bv,
                  const int* __restrict__ flagp,
                  float* __restrict__ Qf32, float* __restrict__ Kf32,
                  u16* __restrict__ Khf, u16* __restrict__ Vhf) {
    __shared__ float Xs[64][68];
    __shared__ float Ws[64][68];
    int f32 = *flagp;
    int z = blockIdx.z;
    const void* X = (z == 0) ? query : ((z == 1) ? key : value);
    const void* W = (z == 0) ? wq : ((z == 1) ? wk : wv);
    const void* Bv = (z == 0) ? bq : ((z == 1) ? bk : bv);
    float* Y = (z == 0) ? Qf32 : Kf32;       // z==2 has no f32 output
    int c0 = blockIdx.x * 64, r0 = blockIdx.y * 64;
    int tx = threadIdx.x & 15, ty = threadIdx.x >> 4;

    int sr[4], sq[4];
    #pragma unroll
    for (int it = 0; it < 4; ++it) {
        int idx = threadIdx.x + it * 256;
        sr[it] = idx >> 4;        // row 0..63
        sq[it] = idx & 15;        // float4 slot 0..15
    }

    float4 xr[4], wr[4];
    if (f32) {
        #pragma unroll
        for (int it = 0; it < 4; ++it) {
            xr[it] = *reinterpret_cast<const float4*>((const float*)X + (size_t)(r0 + sr[it]) * DDM + sq[it] * 4);
            wr[it] = *reinterpret_cast<const float4*>((const float*)W + (size_t)sr[it] * DDM + c0 + sq[it] * 4);
        }
    } else {
        #pragma unroll
        for (int it = 0; it < 4; ++it) {
            ushort4 xh = *reinterpret_cast<const ushort4*>((const u16*)X + (size_t)(r0 + sr[it]) * DDM + sq[it] * 4);
            ushort4 wh = *reinterpret_cast<const ushort4*>((const u16*)W + (size_t)sr[it] * DDM + c0 + sq[it] * 4);
            xr[it] = make_float4(bf2f(xh.x), bf2f(xh.y), bf2f(xh.z), bf2f(xh.w));
            wr[it] = make_float4(bf2f(wh.x), bf2f(wh.y), bf2f(wh.z), bf2f(wh.w));
        }
    }

    float acc[4][4] = {};
    for (int k0 = 0; k0 < DDM; k0 += 64) {
        __syncthreads();
        #pragma unroll
        for (int it = 0; it < 4; ++it) {
            *reinterpret_cast<float4*>(&Xs[sr[it]][sq[it] * 4]) = xr[it];
            *reinterpret_cast<float4*>(&Ws[sr[it]][sq[it] * 4]) = wr[it];
        }
        __syncthreads();
        int kn = k0 + 64;
        if (kn < DDM) {
            if (f32) {
                #pragma unroll
                for (int it = 0; it < 4; ++it) {
                    xr[it] = *reinterpret_cast<const float4*>((const float*)X + (size_t)(r0 + sr[it]) * DDM + kn + sq[it] * 4);
                    wr[it] = *reinterpret_cast<const float4*>((const float*)W + (size_t)(kn + sr[it]) * DDM + c0 + sq[it] * 4);
                }
            } else {
                #pragma unroll
                for (int it = 0; it < 4; ++it) {
                    ushort4 xh = *reinterpret_cast<const ushort4*>((const u16*)X + (size_t)(r0 + sr[it]) * DDM + kn + sq[it] * 4);
                    ushort4 wh = *reinterpret_cast<const ushort4*>((const u16*)W + (size_t)(kn + sr[it]) * DDM + c0 + sq[it] * 4);
                    xr[it] = make_float4(bf2f(xh.x), bf2f(xh.y), bf2f(xh.z), bf2f(xh.w));
                    wr[it] = make_float4(bf2f(wh.x), bf2f(wh.y), bf2f(wh.z), bf2f(wh.w));
                }
            }
        }
        // EXACT compute (unchanged): sub-k ascending per output element
        #pragma unroll 4
        for (int kk = 0; kk < 64; kk += 4) {
            float4 xv[4];
            #pragma unroll
            for (int a = 0; a < 4; ++a)
                xv[a] = *reinterpret_cast<const float4*>(&Xs[ty + 16 * a][kk]);
            #pragma unroll
            for (int j = 0; j < 4; ++j) {
                float4 wv = *reinterpret_cast<const float4*>(&Ws[kk + j][4 * tx]);
                #pragma unroll
                for (int a = 0; a < 4; ++a) {
                    float x = ((const float*)&xv[a])[j];
                    acc[a][0] = fmaf(x, wv.x, acc[a][0]);
                    acc[a][1] = fmaf(x, wv.y, acc[a][1]);
                    acc[a][2] = fmaf(x, wv.z, acc[a][2]);
                    acc[a][3] = fmaf(x, wv.w, acc[a][3]);
                }
            }
        }
    }
    #pragma unroll
    for (int a = 0; a < 4; ++a) {
        int r = r0 + ty + 16 * a;
        float4 o;
        o.x = acc[a][0] + ldin(Bv, c0 + 4 * tx + 0, f32);
        o.y = acc[a][1] + ldin(Bv, c0 + 4 * tx + 1, f32);
        o.z = acc[a][2] + ldin(Bv, c0 + 4 * tx + 2, f32);
        o.w = acc[a][3] + ldin(Bv, c0 + 4 * tx + 3, f32);
        if (z != 2)
            *reinterpret_cast<float4*>(&Y[(size_t)r * DDM + c0 + 4 * tx]) = o;
        if (z != 0) {
            uint2 ph;
            ph.x = packh2(o.x, o.y);
            ph.y = packh2(o.z, o.w);
            u16* dst = (z == 1) ? Khf : Vhf;
            *reinterpret_cast<uint2*>(&dst[(size_t)r * DDM + c0 + 4 * tx]) = ph;
        }
    }
}

// ---------------------------------------------------------------------------
// K3 v4 (round-6 best-total version): f32 scores. EXACT-SENSITIVE per-element
// FMA chain UNCHANGED. 128x64 macro-tile, 8x4/thread, 256 threads. Structural
// floor for the exact-chain constraint (r6/r7/r8 variants all 104-108us).
// ---------------------------------------------------------------------------
__global__ __launch_bounds__(256, 2)
void scoresf_kernel(const float* __restrict__ Qf32, const float* __restrict__ Kf32,
                    float* __restrict__ S3f) {
    __shared__ float Qs[128][68];
    __shared__ float Ks[64][68];
    int b = blockIdx.z;
    const float* Qb = Qf32 + (size_t)b * SSQ * DDM;
    const float* Kb = Kf32 + (size_t)b * SSQ * DDM;
    float* S3 = S3f + (size_t)b * SSQ * SSQ;
    int j0 = blockIdx.x * 64, i0 = blockIdx.y * 128;
    int tx = threadIdx.x & 15, ty = threadIdx.x >> 4;

    int qr_r[8], qr_s[8], kr_r[4], kr_s[4];
    #pragma unroll
    for (int it = 0; it < 8; ++it) {
        int idx = threadIdx.x + it * 256;
        qr_r[it] = idx >> 4;
        qr_s[it] = idx & 15;
    }
    #pragma unroll
    for (int it = 0; it < 4; ++it) {
        int idx = threadIdx.x + it * 256;
        kr_r[it] = idx >> 4;
        kr_s[it] = idx & 15;
    }

    float4 qr[8], kr[4];
    #pragma unroll
    for (int it = 0; it < 8; ++it)
        qr[it] = *reinterpret_cast<const float4*>(Qb + (size_t)(i0 + qr_r[it]) * DDM + qr_s[it] * 4);
    #pragma unroll
    for (int it = 0; it < 4; ++it)
        kr[it] = *reinterpret_cast<const float4*>(Kb + (size_t)(j0 + kr_r[it]) * DDM + kr_s[it] * 4);

    float acc[8][4] = {};
    for (int k0 = 0; k0 < DDM; k0 += 64) {
        __syncthreads();
        #pragma unroll
        for (int it = 0; it < 8; ++it)
            *reinterpret_cast<float4*>(&Qs[qr_r[it]][qr_s[it] * 4]) = qr[it];
        #pragma unroll
        for (int it = 0; it < 4; ++it)
            *reinterpret_cast<float4*>(&Ks[kr_r[it]][kr_s[it] * 4]) = kr[it];
        __syncthreads();
        int kn = k0 + 64;
        if (kn < DDM) {
            #pragma unroll
            for (int it = 0; it < 8; ++it)
                qr[it] = *reinterpret_cast<const float4*>(Qb + (size_t)(i0 + qr_r[it]) * DDM + kn + qr_s[it] * 4);
            #pragma unroll
            for (int it = 0; it < 4; ++it)
                kr[it] = *reinterpret_cast<const float4*>(Kb + (size_t)(j0 + kr_r[it]) * DDM + kn + kr_s[it] * 4);
        }
        #pragma unroll 2
        for (int kk = 0; kk < 64; kk += 4) {
            float4 qv[8], kv[4];
            #pragma unroll
            for (int a = 0; a < 8; ++a)
                qv[a] = *reinterpret_cast<const float4*>(&Qs[ty + 16 * a][kk]);
            #pragma unroll
            for (int b2 = 0; b2 < 4; ++b2)
                kv[b2] = *reinterpret_cast<const float4*>(&Ks[tx + 16 * b2][kk]);
            #pragma unroll
            for (int a = 0; a < 8; ++a)
                #pragma unroll
                for (int b2 = 0; b2 < 4; ++b2) {   // .x,.y,.z,.w ascending: exact
                    acc[a][b2] = fmaf(qv[a].x, kv[b2].x, acc[a][b2]);
                    acc[a][b2] = fmaf(qv[a].y, kv[b2].y, acc[a][b2]);
                    acc[a][b2] = fmaf(qv[a].z, kv[b2].z, acc[a][b2]);
                    acc[a][b2] = fmaf(qv[a].w, kv[b2].w, acc[a][b2]);
                }
        }
    }
    __syncthreads();
    #pragma unroll
    for (int a = 0; a < 8; ++a)
        #pragma unroll
        for (int b2 = 0; b2 < 4; ++b2)
            Qs[ty + 16 * a][tx + 16 * b2] = acc[a][b2] * 0.125f;
    __syncthreads();
    #pragma unroll
    for (int it = 0; it < 8; ++it) {
        int row = qr_r[it], q4 = qr_s[it];
        float4 o = *reinterpret_cast<const float4*>(&Qs[row][q4 * 4]);
        *reinterpret_cast<float4*>(&S3[(size_t)(i0 + row) * SSQ + j0 + q4 * 4]) = o;
    }
}

// ---------------------------------------------------------------------------
// K4 v2: per-row top-204 via 4-pass radix select (validated) + compact
// column lists (validated round 7).
// ---------------------------------------------------------------------------
__global__ __launch_bounds__(256)
void maskselect_kernel(const float* __restrict__ S3f,
                       u64* __restrict__ bitmask,     // (B*S, 16)
                       u16* __restrict__ lists) {     // (B*S, 256)
    __shared__ u32 keys[1024];
    __shared__ u32 sel[1024];
    __shared__ u32 hist[256];
    __shared__ u32 ssum[256];
    __shared__ u32 scan[256];
    __shared__ u32 pick_digit, pick_rem;
    int i = blockIdx.x, b = blockIdx.y;
    int t = threadIdx.x;
    const float* srow = S3f + (size_t)b * SSQ * SSQ + (size_t)i * SSQ;
    for (int j = t; j < 1024; j += 256) {
        u32 bits = __float_as_uint(srow[j]);
        keys[j] = (bits & 0x80000000u) ? ~bits : (bits | 0x80000000u);
    }
    __syncthreads();
    u32 prefix = 0, himask = 0, rem = KTOP;
    for (int p = 3; p >= 0; --p) {
        int shift = p * 8;
        hist[t] = 0;
        __syncthreads();
        for (int j = t; j < 1024; j += 256) {
            u32 kb = keys[j];
            if ((kb & himask) == prefix) atomicAdd(&hist[(kb >> shift) & 0xFFu], 1u);
        }
        __syncthreads();
        ssum[t] = hist[t];
        __syncthreads();
        for (int off = 1; off < 256; off <<= 1) {
            u32 v = (t + off < 256) ? ssum[t + off] : 0u;
            __syncthreads();
            ssum[t] += v;
            __syncthreads();
        }
        u32 nxt = (t < 255) ? ssum[t + 1] : 0u;
        if (ssum[t] >= rem && nxt < rem) { pick_digit = (u32)t; pick_rem = rem - nxt; }
        __syncthreads();
        prefix |= pick_digit << shift;
        rem = pick_rem;
        himask |= (0xFFu << shift);
        __syncthreads();
    }
    u32 vstar = prefix;
    u32 tneed = rem;
    u32 eq[4]; u32 local = 0;
    #pragma unroll
    for (int a = 0; a < 4; ++a) {
        int j = 4 * t + a;
        u32 kb = keys[j];
        sel[j] = (kb > vstar) ? 1u : 0u;
        eq[a] = (kb == vstar) ? 1u : 0u;
        local += eq[a];
    }
    scan[t] = local;
    __syncthreads();
    for (int off = 1; off < 256; off <<= 1) {
        u32 v = (t >= off) ? scan[t - off] : 0u;
        __syncthreads();
        scan[t] += v;
        __syncthreads();
    }
    u32 base = (t > 0) ? scan[t - 1] : 0u;
    #pragma unroll
    for (int a = 0; a < 4; ++a) {
        if (eq[a]) { if (base < tneed) sel[4 * t + a] = 1u; base += 1; }
    }
    __syncthreads();
    if (t < 16) {
        u64 wbits = 0;
        for (int l = 0; l < 64; ++l)
            if (sel[t * 64 + l]) wbits |= (1ull << l);
        bitmask[((size_t)b * SSQ + i) * 16 + t] = wbits;
    }
    // --- compact selected columns (exactly KTOP, ascending order) ---
    u32 ones = sel[4 * t] + sel[4 * t + 1] + sel[4 * t + 2] + sel[4 * t + 3];
    scan[t] = ones;
    __syncthreads();
    for (int off = 1; off < 256; off <<= 1) {
        u32 v = (t >= off) ? scan[t - off] : 0u;
        __syncthreads();
        scan[t] += v;
        __syncthreads();
    }
    u32 pos = scan[t] - ones;
    u16* lrow = lists + ((size_t)b * SSQ + i) * 256;
    #pragma unroll
    for (int a = 0; a < 4; ++a) {
        if (sel[4 * t + a]) lrow[pos++] = (u16)(4 * t + a);
    }
    if (t < 52) lrow[KTOP + t] = 0;   // pad tail (keeps garbage out of staging)
}

// ---------------------------------------------------------------------------
// K5 v5: sparse attention. One wave per (b,h,i) row. Loose-tolerance path.
//  - column list precomputed by maskselect (cnt == KTOP always).
//  - score phase: fp16 K + v_dot2_f32_f16, 4 lanes/column (validated).
//  - V phase: fp16 V + v_fma_mix_f32, 8 lanes/entry (validated).
// ---------------------------------------------------------------------------
__global__ __launch_bounds__(256, 8)
void attn_sparse_kernel(const float* __restrict__ Qf32, const u16* __restrict__ Khf,
                        const u16* __restrict__ Vhf, const u16* __restrict__ lists,
                        float* __restrict__ AO) {
    __shared__ float pbuf[4][256];
    __shared__ uint2 lraw[4][64];
    int lane = threadIdx.x & 63, w = threadIdx.x >> 6;
    int b = blockIdx.z, h = blockIdx.y, i = blockIdx.x * 4 + w;
    size_t qoff = ((size_t)(b * SSQ + i)) * DDM + h * 64;

    // --- stage precomputed column list (256 u16 = 64 x uint2) ---
    const uint2* Lrow = reinterpret_cast<const uint2*>(lists + ((size_t)(b * SSQ + i)) * 256);
    lraw[w][lane] = Lrow[lane];
    const u16* list = reinterpret_cast<const u16*>(lraw[w]);

    // --- score phase: 16 columns/iter, 4 lanes cooperate per column ---
    int sub = lane & 3;        // dim-octet selector
    int g   = lane >> 2;       // column group 0..15
    u32 qh[8];                 // Q dims {sub*8..+8} and {32+sub*8..+8} as fp16 pairs
    {
        float4 qa = *reinterpret_cast<const float4*>(&Qf32[qoff + sub * 8]);
        float4 qb = *reinterpret_cast<const float4*>(&Qf32[qoff + sub * 8 + 4]);
        float4 qc = *reinterpret_cast<const float4*>(&Qf32[qoff + 32 + sub * 8]);
        float4 qd = *reinterpret_cast<const float4*>(&Qf32[qoff + 32 + sub * 8 + 4]);
        qh[0] = packh2(qa.x, qa.y); qh[1] = packh2(qa.z, qa.w);
        qh[2] = packh2(qb.x, qb.y); qh[3] = packh2(qb.z, qb.w);
        qh[4] = packh2(qc.x, qc.y); qh[5] = packh2(qc.z, qc.w);
        qh[6] = packh2(qd.x, qd.y); qh[7] = packh2(qd.z, qd.w);
    }

    const u16* Kb = Khf + (size_t)b * SSQ * DDM + h * 64 + sub * 8;
    float m = -1e30f;
    for (int base = 0; base < KTOP; base += 16) {
        int idx = base + g;
        int valid = (idx < KTOP);
        int j = valid ? (int)list[idx] : 0;
        const u16* kr = Kb + (size_t)j * DDM;
        uint4 k0 = *reinterpret_cast<const uint4*>(kr);        // dims sub*8..+8 (line 0)
        uint4 k1 = *reinterpret_cast<const uint4*>(kr + 32);   // dims 32+sub*8..+8 (line 1)
        float p = fdot2f(qh[0], k0.x, 0.f);
        p = fdot2f(qh[1], k0.y, p);
        p = fdot2f(qh[2], k0.z, p);
        p = fdot2f(qh[3], k0.w, p);
        p = fdot2f(qh[4], k1.x, p);
        p = fdot2f(qh[5], k1.y, p);
        p = fdot2f(qh[6], k1.z, p);
        p = fdot2f(qh[7], k1.w, p);
        p += __shfl_xor(p, 1);
        p += __shfl_xor(p, 2);
        float s = valid ? p * 0.125f : -1e30f;
        m = fmaxf(m, s);
        if (valid && sub == 0) pbuf[w][idx] = s;
    }
    #pragma unroll
    for (int off = 32; off >= 1; off >>= 1) m = fmaxf(m, __shfl_xor(m, off));

    // --- softmax: exp in place, wave-sum ---
    float lsum = 0.f;
    for (int idx = lane; idx < KTOP; idx += 64) {
        float p = expf(pbuf[w][idx] - m);
        pbuf[w][idx] = p;
        lsum += p;
    }
    #pragma unroll
    for (int off = 32; off >= 1; off >>= 1) lsum += __shfl_xor(lsum, off);

    // --- V phase: 8 entries/iter, 8 lanes each owning 8 dims (fma_mix) ---
    int vg = lane >> 3, vl = lane & 7;
    const u16* Vb = Vhf + (size_t)b * SSQ * DDM + h * 64 + vl * 8;
    float ac[8] = {};
    #pragma unroll 2
    for (int tt = 0; tt < KTOP; tt += 8) {
        int e = tt + vg;
        if (e < KTOP) {
            int j = (int)list[e];
            float pwt = pbuf[w][e];
            U8H vv;
            vv.u = *reinterpret_cast<const uint4*>(Vb + (size_t)j * DDM);
            ac[0] = fmaf((float)vv.h[0], pwt, ac[0]);
            ac[1] = fmaf((float)vv.h[1], pwt, ac[1]);
            ac[2] = fmaf((float)vv.h[2], pwt, ac[2]);
            ac[3] = fmaf((float)vv.h[3], pwt, ac[3]);
            ac[4] = fmaf((float)vv.h[4], pwt, ac[4]);
            ac[5] = fmaf((float)vv.h[5], pwt, ac[5]);
            ac[6] = fmaf((float)vv.h[6], pwt, ac[6]);
            ac[7] = fmaf((float)vv.h[7], pwt, ac[7]);
        }
    }
    #pragma unroll
    for (int off = 8; off <= 32; off <<= 1) {
        #pragma unroll
        for (int t = 0; t < 8; ++t) ac[t] += __shfl_xor(ac[t], off);
    }
    if (vg == 0) {
        float inv = 1.0f / lsum;
        float4 o0, o1;
        o0.x = ac[0] * inv; o0.y = ac[1] * inv; o0.z = ac[2] * inv; o0.w = ac[3] * inv;
        o1.x = ac[4] * inv; o1.y = ac[5] * inv; o1.z = ac[6] * inv; o1.w = ac[7] * inv;
        *reinterpret_cast<float4*>(&AO[qoff + vl * 8]) = o0;
        *reinterpret_cast<float4*>(&AO[qoff + vl * 8 + 4]) = o1;
    }
}

// ---------------------------------------------------------------------------
// K6 v2 (r7 configuration): output projection  out0 = AO @ wo + bo.
// 64x64 tile, 4x4/thread, 4 blocks/CU (validated best). Staging vectorized +
// register-prefetch pipeline.
// ---------------------------------------------------------------------------
__global__ __launch_bounds__(256, 4)
void outproj_kernel(const float* __restrict__ AO, const void* __restrict__ wo,
                    const void* __restrict__ bo, const int* __restrict__ flagp,
                    float* __restrict__ out0) {
    __shared__ float Xs[64][68];
    __shared__ float Ws[64][68];
    int f32 = *flagp;
    int c0 = blockIdx.x * 64, r0 = blockIdx.y * 64;
    int tx = threadIdx.x & 15, ty = threadIdx.x >> 4;

    int sr[4], sq[4];
    #pragma unroll
    for (int it = 0; it < 4; ++it) {
        int idx = threadIdx.x + it * 256;
        sr[it] = idx >> 4;
        sq[it] = idx & 15;
    }

    float4 xr[4], wr[4];
    #pragma unroll
    for (int it = 0; it < 4; ++it)
        xr[it] = *reinterpret_cast<const float4*>(AO + (size_t)(r0 + sr[it]) * DDM + sq[it] * 4);
    if (f32) {
        #pragma unroll
        for (int it = 0; it < 4; ++it)
            wr[it] = *reinterpret_cast<const float4*>((const float*)wo + (size_t)sr[it] * DDM + c0 + sq[it] * 4);
    } else {
        #pragma unroll
        for (int it = 0; it < 4; ++it) {
            ushort4 wh = *reinterpret_cast<const ushort4*>((const u16*)wo + (size_t)sr[it] * DDM + c0 + sq[it] * 4);
            wr[it] = make_float4(bf2f(wh.x), bf2f(wh.y), bf2f(wh.z), bf2f(wh.w));
        }
    }

    float acc[4][4] = {};
    for (int k0 = 0; k0 < DDM; k0 += 64) {
        __syncthreads();
        #pragma unroll
        for (int it = 0; it < 4; ++it) {
            *reinterpret_cast<float4*>(&Xs[sr[it]][sq[it] * 4]) = xr[it];
            *reinterpret_cast<float4*>(&Ws[sr[it]][sq[it] * 4]) = wr[it];
        }
        __syncthreads();
        int kn = k0 + 64;
        if (kn < DDM) {
            #pragma unroll
            for (int it = 0; it < 4; ++it)
                xr[it] = *reinterpret_cast<const float4*>(AO + (size_t)(r0 + sr[it]) * DDM + kn + sq[it] * 4);
            if (f32) {
                #pragma unroll
                for (int it = 0; it < 4; ++it)
                    wr[it] = *reinterpret_cast<const float4*>((const float*)wo + (size_t)(kn + sr[it]) * DDM + c0 + sq[it] * 4);
            } else {
                #pragma unroll
                for (int it = 0; it < 4; ++it) {
                    ushort4 wh = *reinterpret_cast<const ushort4*>((const u16*)wo + (size_t)(kn + sr[it]) * DDM + c0 + sq[it] * 4);
                    wr[it] = make_float4(bf2f(wh.x), bf2f(wh.y), bf2f(wh.z), bf2f(wh.w));
                }
            }
        }
        #pragma unroll 4
        for (int kk = 0; kk < 64; kk += 4) {
            float4 xv[4];
            #pragma unroll
            for (int a = 0; a < 4; ++a)
                xv[a] = *reinterpret_cast<const float4*>(&Xs[ty + 16 * a][kk]);
            #pragma unroll
            for (int j = 0; j < 4; ++j) {
                float4 wv = *reinterpret_cast<const float4*>(&Ws[kk + j][4 * tx]);
                #pragma unroll
                for (int a = 0; a < 4; ++a) {
                    float x = ((const float*)&xv[a])[j];
                    acc[a][0] = fmaf(x, wv.x, acc[a][0]);
                    acc[a][1] = fmaf(x, wv.y, acc[a][1]);
                    acc[a][2] = fmaf(x, wv.z, acc[a][2]);
                    acc[a][3] = fmaf(x, wv.w, acc[a][3]);
                }
            }
        }
    }
    #pragma unroll
    for (int a = 0; a < 4; ++a) {
        int r = r0 + ty + 16 * a;
        float4 o;
        o.x = acc[a][0] + ldin(bo, c0 + 4 * tx + 0, f32);
        o.y = acc[a][1] + ldin(bo, c0 + 4 * tx + 1, f32);
        o.z = acc[a][2] + ldin(bo, c0 + 4 * tx + 2, f32);
        o.w = acc[a][3] + ldin(bo, c0 + 4 * tx + 3, f32);
        *reinterpret_cast<float4*>(&out0[(size_t)r * DDM + c0 + 4 * tx]) = o;
    }
}

// ---------------------------------------------------------------------------
// K7 (last): expand bitmask -> f32 mask for all 8 heads, overwriting ALL of
// out1 (which served as scratch until now). One block per (b,i) row.
// ---------------------------------------------------------------------------
__global__ __launch_bounds__(256)
void maskwrite_kernel(const u64* __restrict__ bitmask,
                      float* __restrict__ out1) {
    int row = blockIdx.x;            // b*S + i
    int t = threadIdx.x;
    int b = row >> 10, i = row & 1023;
    const u64* mb = bitmask + (size_t)row * 16;
    int j0 = t * 4;
    u64 w0 = mb[j0 >> 6];
    float4 v4;
    v4.x = ((w0 >> (j0 & 63)) & 1ull) ? 1.0f : 0.0f;
    v4.y = ((w0 >> ((j0 + 1) & 63)) & 1ull) ? 1.0f : 0.0f;
    v4.z = ((w0 >> ((j0 + 2) & 63)) & 1ull) ? 1.0f : 0.0f;
    v4.w = ((w0 >> ((j0 + 3) & 63)) & 1ull) ? 1.0f : 0.0f;
    for (int h = 0; h < HHD; ++h) {
        size_t base_o = (((size_t)b * HHD + h) * SSQ + i) * SSQ;
        *reinterpret_cast<float4*>(out1 + base_o + (size_t)t * 4) = v4;
    }
}

// ---------------------------------------------------------------------------
extern "C" void kernel_launch(void* const* d_in, const int* in_sizes, int n_in,
                              void* d_out, int out_size, void* d_ws, size_t ws_size,
                              hipStream_t stream) {
    const void* query = d_in[0];
    const void* key   = d_in[1];
    const void* value = d_in[2];
    const void* wq = d_in[3];  const void* bq = d_in[4];
    const void* wk = d_in[5];  const void* bk = d_in[6];
    const void* wv = d_in[7];  const void* bv = d_in[8];
    const void* wo = d_in[9];  const void* bo = d_in[10];
    const void* pw1 = d_in[11]; const void* pb1 = d_in[12];
    const void* pw2 = d_in[13]; const void* pb2 = d_in[14];
    const void* pattern_bank = d_in[15];
    const void* pattern_gate = d_in[16];

    // Outputs are FLOAT32 (validated round 8).
    float* out0 = (float*)d_out;                          // (B,S,D)   2M f32
    float* out1 = out0 + (size_t)BB * SSQ * DDM;          // (B,H,S,S) 33.5M f32 (134MB)
    float* out2 = out1 + (size_t)BB * HHD * SSQ * SSQ;    // (B,S,NP)  32K f32

    // d_ws: tiny header only (dtype flag + 512KB bitmask).
    int* flag = (int*)d_ws;
    u64* bitmask = (u64*)((char*)d_ws + 65536);           // (B*S,16) = 512KB

    // All large scratch lives INSIDE out1's 134MB, overwritten by maskwrite.
    char* SCR = (char*)out1;
    float* Qf32 = (float*)(SCR);                          // [0,8M)
    float* Kf32 = (float*)(SCR + (8ull << 20));           // [8M,16M)
    float* AO   = (float*)(SCR + (24ull << 20));          // [24M,32M)
    float* S3f  = (float*)(SCR + (32ull << 20));          // [32M,48M) all-batch scores
    u16*   Khf  = (u16*)  (SCR + (48ull << 20));          // [48M,52M) fp16 K
    u16*   Vhf  = (u16*)  (SCR + (52ull << 20));          // [52M,56M) fp16 V
    u16*   lists= (u16*)  (SCR + (56ull << 20));          // [56M,58M) column lists

    detect_kernel<<<dim3(1), dim3(64), 0, stream>>>(query, flag);

    pattern_kernel<<<dim3(BB * SSQ), dim3(64), 0, stream>>>(
        query, pw1, pb1, pw2, pb2, pattern_bank, pattern_gate, flag, out2);

    // f32 Q/K projections + fp16 K/V (exact sequential-FMA-chain semantics;
    // Vf32 dead since attn moved to fp16 V)
    projf_kernel<<<dim3(DDM / 64, BB * SSQ / 64, 3), dim3(256), 0, stream>>>(
        query, key, value, wq, bq, wk, bk, wv, bv, flag, Qf32, Kf32, Khf, Vhf);

    // f32 scores, all batches in one launch (128x64 macro-tile, best-total cfg)
    scoresf_kernel<<<dim3(SSQ / 64, SSQ / 128, BB), dim3(256), 0, stream>>>(
        Qf32, Kf32, S3f);

    // top-204 per row + compacted column lists
    maskselect_kernel<<<dim3(SSQ, BB), dim3(256), 0, stream>>>(S3f, bitmask, lists);

    // sparse attention over the 204 active columns (fp16 K dot2, fp16 V fma_mix)
    attn_sparse_kernel<<<dim3(SSQ / 4, HHD, BB), dim3(256), 0, stream>>>(
        Qf32, Khf, Vhf, lists, AO);

    outproj_kernel<<<dim3(DDM / 64, BB * SSQ / 64), dim3(256), 0, stream>>>(
        AO, wo, bo, flag, out0);

    // LAST: expand bitmask into out1 (f32 mask), erasing all scratch
    maskwrite_kernel<<<dim3(BB * SSQ), dim3(256), 0, stream>>>(bitmask, out1);
}